// Round 5
// baseline (1352.979 us; speedup 1.0000x reference)
//
#include <hip/hip_runtime.h>

// LSTM autoencoder B=2048,T=128: L1 LSTM(128,in1) -> L2 LSTM(64,in128) -> Repeat
// -> L3 LSTM(64,in64) -> L4 LSTM(128,in64) -> Dense(1).
// R18 = CROSS-LAYER WAVE-SPECIALIZED PIPELINE (lag-1 software pipelining).
// Evidence: R14/R16 (register residency) and R17 (LDS staging) prove the weight
// path is NOT the bottleneck (486/489/490us invariant). The invariant is the
// step STRUCTURE: L1(8 waves) -> barrier -> L2(waves 0-3, 1/SIMD, waves 4-7
// idle) exposes L2's full latency chain serially; ~57% of cycles issue nothing.
// Dependency graph: L1(t) needs {h1(t-1),x}; L2(s) needs {h1(s),h2(s-1)} ->
// L1(t) iz independent of L2(t-1). R18 runs them CONCURRENTLY on different
// wave groups: waves 4-7 = L1(t) (8 jt-blocks/wave), waves 0-3 = L2(t-1).
// Phase B: waves 0-3 = L3(t) + dense(t-2), waves 4-7 = L4(t-1).
// One barrier/step; step cost = max(groups) not sum. All cross-group reads hit
// buffers written before the barrier (h1 ping-pong; h2/h4 parity; h3 ping-pong).
// Epilogues: L2(127) after loop A; L4(127)+dense(126), then dense(127) after
// loop B. Weights stream from global/L2 (R17: LDS staging neutral; wlds gone).

#define TSEQ 128
#define NTH  512
#define BSTR 408   // bU row stride in shorts

typedef __attribute__((ext_vector_type(8))) short bf16x8;
typedef __attribute__((ext_vector_type(4))) float f32x4;
typedef __attribute__((ext_vector_type(2))) float f32x2;
typedef __attribute__((ext_vector_type(4))) short s16x4;
typedef unsigned short ushort_t;

// frag regions in d_ws (units of 512-elem frags, 1KB each); hi even, lo odd (lo unused)
#define FB_L1 0      // U1: K=128 (KT=4), JT=32 -> 256 frags
#define FB_L2 256    // [W2;U2]: K=192 (KT=6), JT=16 -> 192
#define FB_L3 448    // U3: K=64 (KT=2), JT=16 -> 64
#define FB_L4 512    // [W4;U4]: K=192 (KT=6), JT=32 -> 384
#define FB_W3 896    // W3: K=64 (KT=2), JT=16 -> 64
#define WS_FRAGS 960
#define WS_NEEDED (WS_FRAGS * 1024)

__device__ __forceinline__ ushort_t f2bf(float f) {
    union { float f; unsigned u; } a; a.f = f;
    unsigned r = a.u + 0x7FFF + ((a.u >> 16) & 1);
    return (ushort_t)(r >> 16);
}
__device__ __forceinline__ float bf2f(ushort_t h) {
    union { unsigned u; float f; } a; a.u = ((unsigned)h) << 16;
    return a.f;
}
__device__ __forceinline__ float sigm(float z) { return 1.0f / (1.0f + __expf(-z)); }

__device__ __forceinline__ f32x4 MF(bf16x8 a, bf16x8 b, f32x4 c) {
    return __builtin_amdgcn_mfma_f32_16x16x32_bf16(a, b, c, 0, 0, 0);
}

// packed f32x2 -> bf16x2 (RNE), 1 instruction; dst[15:0]=lo, dst[31:16]=hi
__device__ __forceinline__ unsigned cvtpk(float lo, float hi) {
    unsigned r;
    asm("v_cvt_pk_bf16_f32 %0, %1, %2" : "=v"(r) : "v"(lo), "v"(hi));
    return r;
}

// ---------------- weight pack kernel (unchanged layout) ----------------
__global__ void pack_weights(const float* __restrict__ U1, const float* __restrict__ W2,
                             const float* __restrict__ U2, const float* __restrict__ U3,
                             const float* __restrict__ W4, const float* __restrict__ U4,
                             const float* __restrict__ W3, ushort_t* __restrict__ out)
{
    const int f = blockIdx.x;
    const int lane = threadIdx.x;
    int fl, KT, ldm, ksplit = 1 << 30, ld2 = 0;
    const float *base, *base2 = nullptr;
    if (f < 256)      { fl = f;       KT = 4; ldm = 512; base = U1; }
    else if (f < 448) { fl = f - 256; KT = 6; ldm = 256; base = W2; ksplit = 128; base2 = U2; ld2 = 256; }
    else if (f < 512) { fl = f - 448; KT = 2; ldm = 256; base = U3; }
    else if (f < 896) { fl = f - 512; KT = 6; ldm = 512; base = W4; ksplit = 64;  base2 = U4; ld2 = 512; }
    else              { fl = f - 896; KT = 2; ldm = 256; base = W3; }
    const int jt = fl / (KT * 2);
    const int rem = fl % (KT * 2);
    const int kt = rem >> 1;
    const int s = rem & 1;
    const int j = jt * 16 + (lane & 15);
    ushort_t* o = out + f * 512 + lane * 8;
    #pragma unroll
    for (int i = 0; i < 8; ++i) {
        const int k = kt * 32 + (lane >> 4) * 8 + i;
        const float w = (k < ksplit) ? base[k * ldm + j] : base2[(k - ksplit) * ld2 + j];
        const ushort_t hi = f2bf(w);
        o[i] = s ? f2bf(w - bf2f(hi)) : hi;
    }
}

// ---------------- main kernel ----------------
__global__ __launch_bounds__(NTH, 2) void lstm_mfma_kernel(
    const float* __restrict__ x,
    const float* __restrict__ W1, const float* __restrict__ b1,
    const float* __restrict__ b2, const float* __restrict__ b3,
    const float* __restrict__ b4,
    const float* __restrict__ Wd, const float* __restrict__ bd,
    const ushort_t* __restrict__ wsp,
    float* __restrict__ out)
{
    // bU: single bf16 activation plane:
    //  phaseA: h1 ping[0,128)/pong[128,256); h2(s) at 256 + (s&1)*64
    //  phaseB: h3 ping[0,64)/pong[64,128);  h4(s) at 128 + (s&1)*128
    __shared__ __align__(16) ushort_t bU[16][BSTR];      // 13056 B
    __shared__ __align__(16) float obuf[16][128];        //  8192 B
    __shared__ __align__(16) float xls[16][132];         //  8448 B
    __shared__ __align__(16) float w1ls[512], b1ls[512], b4ls[512], b2ls[256];

    const int tid  = threadIdx.x;
    const int wid  = tid >> 6;
    const int lane = tid & 63;
    const int quad = lane >> 4;
    const int l15  = lane & 15;
    const int w4   = wid - 4;              // group-1 wave index (waves 4-7)
    const int r0   = blockIdx.x * 16;
    const bf16x8* A = (const bf16x8*)wsp;

    // ---- init: zero state, stage x / W1 / biases ----
    {
        unsigned* p = (unsigned*)&bU[0][0];
        for (int i = tid; i < 16 * BSTR / 2; i += NTH) p[i] = 0u;
        const int srow = tid >> 5, scol = (tid & 31) * 4;
        *(f32x4*)&xls[srow][scol] = *(const f32x4*)&x[(r0 + srow) * TSEQ + scol];
        w1ls[tid] = W1[tid];
        b1ls[tid] = b1[tid];
        b4ls[tid] = b4[tid];
        if (tid < 256) b2ls[tid] = b2[tid];
    }

    const float wd0 = Wd[lane], wd1 = Wd[64 + lane], bd0 = bd[0];

    __syncthreads();

    // ================= Phase A: waves 4-7 = L1(t), waves 0-3 = L2(t-1) ========
    {
        float c1r[8] = {0.f};   // G1: c-state, 2 col-blocks x 4
        float c2r[4] = {0.f};   // G2

        for (int t = 0; t < TSEQ; ++t) {
            __syncthreads();
            const int rb1 = (t & 1) * 128, wb1 = 128 - rb1;   // h1(t-1) / h1(t)

            if (wid >= 4) {
                // ---- L1(t): 8 jt-blocks per wave ----
                bf16x8 Bh[4];
                #pragma unroll
                for (int kt = 0; kt < 4; ++kt)
                    Bh[kt] = *(const bf16x8*)&bU[l15][rb1 + kt * 32 + quad * 8];
                const float xr = xls[l15][t];
                f32x4 acc[4][2];
                #pragma unroll
                for (int g = 0; g < 4; ++g)
                    #pragma unroll
                    for (int d = 0; d < 2; ++d) {
                        const int jt_ = 8 * g + w4 + 4 * d;
                        const int jb = jt_ * 16 + quad * 4;
                        f32x4 a = *(const f32x4*)&b1ls[jb];
                        a += xr * *(const f32x4*)&w1ls[jb];
                        #pragma unroll
                        for (int kt = 0; kt < 4; ++kt)
                            a = MF(A[(FB_L1 + (jt_ * 4 + kt) * 2) * 64 + lane], Bh[kt], a);
                        acc[g][d] = a;
                    }
                #pragma unroll
                for (int d = 0; d < 2; ++d) {
                    float hg[4];
                    #pragma unroll
                    for (int g = 0; g < 4; ++g) {
                        const float zi = acc[0][d][g];
                        const float zf = acc[1][d][g];
                        const float zg = acc[2][d][g];
                        const float zo = acc[3][d][g];
                        const float c = sigm(zf) * c1r[d * 4 + g] + sigm(zi) * fmaxf(zg, 0.f);
                        c1r[d * 4 + g] = c;
                        hg[g] = sigm(zo) * fmaxf(c, 0.f);
                    }
                    uint2 hv;
                    hv.x = cvtpk(hg[0], hg[1]);
                    hv.y = cvtpk(hg[2], hg[3]);
                    *(uint2*)&bU[l15][wb1 + (w4 + 4 * d) * 16 + quad * 4] = hv;
                }
            } else if (t > 0) {
                // ---- L2(t-1): reads h1(t-1)=rb1, h2(t-2); writes h2(t-1) ----
                const int h2rd = 256 + (t & 1) * 64;          // h2(t-2)
                const int h2wr = 256 + ((t & 1) ^ 1) * 64;    // h2(t-1)
                bf16x8 Bh[6];
                #pragma unroll
                for (int kt = 0; kt < 4; ++kt)
                    Bh[kt] = *(const bf16x8*)&bU[l15][rb1 + kt * 32 + quad * 8];
                Bh[4] = *(const bf16x8*)&bU[l15][h2rd + quad * 8];
                Bh[5] = *(const bf16x8*)&bU[l15][h2rd + 32 + quad * 8];
                f32x4 acc[4];
                #pragma unroll
                for (int g = 0; g < 4; ++g) {
                    f32x4 a = *(const f32x4*)&b2ls[(4 * g + wid) * 16 + quad * 4];
                    #pragma unroll
                    for (int kt = 0; kt < 6; ++kt)
                        a = MF(A[(FB_L2 + ((4 * g + wid) * 6 + kt) * 2) * 64 + lane], Bh[kt], a);
                    acc[g] = a;
                }
                float hg[4];
                #pragma unroll
                for (int e = 0; e < 4; ++e) {
                    const float zi = acc[0][e];
                    const float zf = acc[1][e];
                    const float zg = acc[2][e];
                    const float zo = acc[3][e];
                    const float c = sigm(zf) * c2r[e] + sigm(zi) * fmaxf(zg, 0.f);
                    c2r[e] = c;
                    hg[e] = sigm(zo) * fmaxf(c, 0.f);
                }
                uint2 hv;
                hv.x = cvtpk(hg[0], hg[1]);
                hv.y = cvtpk(hg[2], hg[3]);
                *(uint2*)&bU[l15][h2wr + wid * 16 + quad * 4] = hv;
            }
        }
        __syncthreads();
        // epilogue: L2(127) ("t=128"): h1(127) at col 0, h2(126) at 256, write 320
        if (wid < 4) {
            bf16x8 Bh[6];
            #pragma unroll
            for (int kt = 0; kt < 4; ++kt)
                Bh[kt] = *(const bf16x8*)&bU[l15][0 + kt * 32 + quad * 8];
            Bh[4] = *(const bf16x8*)&bU[l15][256 + quad * 8];
            Bh[5] = *(const bf16x8*)&bU[l15][256 + 32 + quad * 8];
            f32x4 acc[4];
            #pragma unroll
            for (int g = 0; g < 4; ++g) {
                f32x4 a = *(const f32x4*)&b2ls[(4 * g + wid) * 16 + quad * 4];
                #pragma unroll
                for (int kt = 0; kt < 6; ++kt)
                    a = MF(A[(FB_L2 + ((4 * g + wid) * 6 + kt) * 2) * 64 + lane], Bh[kt], a);
                acc[g] = a;
            }
            float hg[4];
            #pragma unroll
            for (int e = 0; e < 4; ++e) {
                const float zi = acc[0][e];
                const float zf = acc[1][e];
                const float zg = acc[2][e];
                const float zo = acc[3][e];
                const float c = sigm(zf) * c2r[e] + sigm(zi) * fmaxf(zg, 0.f);
                hg[e] = sigm(zo) * fmaxf(c, 0.f);
            }
            uint2 hv;
            hv.x = cvtpk(hg[0], hg[1]);
            hv.y = cvtpk(hg[2], hg[3]);
            *(uint2*)&bU[l15][320 + wid * 16 + quad * 4] = hv;
        }
    }
    __syncthreads();

    // ================= z3r = b3 + h2_final @ W3 (registers, waves 0-3) =========
    f32x4 z3r[4];
    if (wid < 4) {
        const bf16x8 Bh0 = *(const bf16x8*)&bU[l15][320 + quad * 8];
        const bf16x8 Bh1 = *(const bf16x8*)&bU[l15][320 + 32 + quad * 8];
        #pragma unroll
        for (int g = 0; g < 4; ++g) {
            const int jt = 4 * g + wid;
            f32x4 a = *(const f32x4*)&b3[jt * 16 + quad * 4];
            a = MF(A[(FB_W3 + (jt * 2 + 0) * 2) * 64 + lane], Bh0, a);
            a = MF(A[(FB_W3 + (jt * 2 + 1) * 2) * 64 + lane], Bh1, a);
            z3r[g] = a;
        }
    }
    __syncthreads();
    // re-zero activation plane for phase B
    {
        unsigned* p = (unsigned*)&bU[0][0];
        for (int i = tid; i < 16 * BSTR / 2; i += NTH) p[i] = 0u;
    }

    // ================= Phase B: waves 0-3 = L3(t)+dense(t-2), waves 4-7 = L4(t-1)
    {
        float c3r[4] = {0.f};
        float c4r[8] = {0.f};

        for (int t = 0; t < TSEQ; ++t) {
            __syncthreads();
            const int rb3 = (t & 1) * 64, wb3 = 64 - rb3;     // h3(t-1) / h3(t)
            const int b4rd = 128 + (t & 1) * 128;             // h4(t-2)
            const int b4wr = 128 + ((t & 1) ^ 1) * 128;       // h4(t-1)

            if (wid < 4) {
                // ---- L3(t): acc init = z3r ----
                const bf16x8 Bh0 = *(const bf16x8*)&bU[l15][rb3 + quad * 8];
                const bf16x8 Bh1 = *(const bf16x8*)&bU[l15][rb3 + 32 + quad * 8];
                f32x4 acc[4];
                #pragma unroll
                for (int g = 0; g < 4; ++g) {
                    f32x4 a = z3r[g];
                    a = MF(A[(FB_L3 + ((4 * g + wid) * 2 + 0) * 2) * 64 + lane], Bh0, a);
                    a = MF(A[(FB_L3 + ((4 * g + wid) * 2 + 1) * 2) * 64 + lane], Bh1, a);
                    acc[g] = a;
                }
                float hg[4];
                #pragma unroll
                for (int e = 0; e < 4; ++e) {
                    const float zi = acc[0][e];
                    const float zf = acc[1][e];
                    const float zg = acc[2][e];
                    const float zo = acc[3][e];
                    const float c = sigm(zf) * c3r[e] + sigm(zi) * fmaxf(zg, 0.f);
                    c3r[e] = c;
                    hg[e] = sigm(zo) * fmaxf(c, 0.f);
                }
                uint2 hv;
                hv.x = cvtpk(hg[0], hg[1]);
                hv.y = cvtpk(hg[2], hg[3]);
                *(uint2*)&bU[l15][wb3 + wid * 16 + quad * 4] = hv;

                // ---- dense(t-2): reads h4(t-2) at b4rd; 4 rows per wave ----
                if (t > 1) {
                    #pragma unroll
                    for (int e = 0; e < 4; ++e) {
                        const int r = wid + 4 * e;
                        const float h0 = bf2f(bU[r][b4rd + lane]);
                        const float h1_ = bf2f(bU[r][b4rd + 64 + lane]);
                        float v = h0 * wd0 + h1_ * wd1;
                        v += __shfl_down(v, 32);
                        v += __shfl_down(v, 16);
                        v += __shfl_down(v, 8);
                        v += __shfl_down(v, 4);
                        v += __shfl_down(v, 2);
                        v += __shfl_down(v, 1);
                        if (lane == 0) obuf[r][t - 2] = v + bd0;
                    }
                }
            } else if (t > 0) {
                // ---- L4(t-1): K=192 = [h3(t-1)@rb3 ; h4(t-2)@b4rd] ----
                bf16x8 Bh[6];
                #pragma unroll
                for (int kt = 0; kt < 2; ++kt)
                    Bh[kt] = *(const bf16x8*)&bU[l15][rb3 + kt * 32 + quad * 8];
                #pragma unroll
                for (int kt = 2; kt < 6; ++kt)
                    Bh[kt] = *(const bf16x8*)&bU[l15][b4rd + (kt - 2) * 32 + quad * 8];
                f32x4 acc[4][2];
                #pragma unroll
                for (int g = 0; g < 4; ++g)
                    #pragma unroll
                    for (int d = 0; d < 2; ++d) {
                        const int jt_ = 8 * g + w4 + 4 * d;
                        f32x4 a = *(const f32x4*)&b4ls[jt_ * 16 + quad * 4];
                        #pragma unroll
                        for (int kt = 0; kt < 6; ++kt)
                            a = MF(A[(FB_L4 + (jt_ * 6 + kt) * 2) * 64 + lane], Bh[kt], a);
                        acc[g][d] = a;
                    }
                #pragma unroll
                for (int d = 0; d < 2; ++d) {
                    float hg[4];
                    #pragma unroll
                    for (int g = 0; g < 4; ++g) {
                        const float zi = acc[0][d][g];
                        const float zf = acc[1][d][g];
                        const float zg = acc[2][d][g];
                        const float zo = acc[3][d][g];
                        const float c = sigm(zf) * c4r[d * 4 + g] + sigm(zi) * fmaxf(zg, 0.f);
                        c4r[d * 4 + g] = c;
                        hg[g] = sigm(zo) * fmaxf(c, 0.f);
                    }
                    uint2 hv;
                    hv.x = cvtpk(hg[0], hg[1]);
                    hv.y = cvtpk(hg[2], hg[3]);
                    *(uint2*)&bU[l15][b4wr + (w4 + 4 * d) * 16 + quad * 4] = hv;
                }
            }
        }
        __syncthreads();
        // epilogue 1 ("t=128"): G1: L4(127); G2: dense(126)
        // h3(127)@0, h4(126)@128, write h4(127)@256
        if (wid >= 4) {
            bf16x8 Bh[6];
            #pragma unroll
            for (int kt = 0; kt < 2; ++kt)
                Bh[kt] = *(const bf16x8*)&bU[l15][0 + kt * 32 + quad * 8];
            #pragma unroll
            for (int kt = 2; kt < 6; ++kt)
                Bh[kt] = *(const bf16x8*)&bU[l15][128 + (kt - 2) * 32 + quad * 8];
            f32x4 acc[4][2];
            #pragma unroll
            for (int g = 0; g < 4; ++g)
                #pragma unroll
                for (int d = 0; d < 2; ++d) {
                    const int jt_ = 8 * g + w4 + 4 * d;
                    f32x4 a = *(const f32x4*)&b4ls[jt_ * 16 + quad * 4];
                    #pragma unroll
                    for (int kt = 0; kt < 6; ++kt)
                        a = MF(A[(FB_L4 + (jt_ * 6 + kt) * 2) * 64 + lane], Bh[kt], a);
                    acc[g][d] = a;
                }
            #pragma unroll
            for (int d = 0; d < 2; ++d) {
                float hg[4];
                #pragma unroll
                for (int g = 0; g < 4; ++g) {
                    const float zi = acc[0][d][g];
                    const float zf = acc[1][d][g];
                    const float zg = acc[2][d][g];
                    const float zo = acc[3][d][g];
                    const float c = sigm(zf) * c4r[d * 4 + g] + sigm(zi) * fmaxf(zg, 0.f);
                    hg[g] = sigm(zo) * fmaxf(c, 0.f);
                }
                uint2 hv;
                hv.x = cvtpk(hg[0], hg[1]);
                hv.y = cvtpk(hg[2], hg[3]);
                *(uint2*)&bU[l15][256 + (w4 + 4 * d) * 16 + quad * 4] = hv;
            }
        } else {
            #pragma unroll
            for (int e = 0; e < 4; ++e) {
                const int r = wid + 4 * e;
                const float h0 = bf2f(bU[r][128 + lane]);
                const float h1_ = bf2f(bU[r][128 + 64 + lane]);
                float v = h0 * wd0 + h1_ * wd1;
                v += __shfl_down(v, 32);
                v += __shfl_down(v, 16);
                v += __shfl_down(v, 8);
                v += __shfl_down(v, 4);
                v += __shfl_down(v, 2);
                v += __shfl_down(v, 1);
                if (lane == 0) obuf[r][126] = v + bd0;
            }
        }
        __syncthreads();
        // epilogue 2: dense(127): h4(127)@256
        if (wid < 4) {
            #pragma unroll
            for (int e = 0; e < 4; ++e) {
                const int r = wid + 4 * e;
                const float h0 = bf2f(bU[r][256 + lane]);
                const float h1_ = bf2f(bU[r][256 + 64 + lane]);
                float v = h0 * wd0 + h1_ * wd1;
                v += __shfl_down(v, 32);
                v += __shfl_down(v, 16);
                v += __shfl_down(v, 8);
                v += __shfl_down(v, 4);
                v += __shfl_down(v, 2);
                v += __shfl_down(v, 1);
                if (lane == 0) obuf[r][127] = v + bd0;
            }
        }
    }
    __syncthreads();
    // coalesced flush: 4 floats/thread
    {
        const int frow = tid >> 5;
        const int fcol = (tid & 31) * 4;
        *(f32x4*)&out[(r0 + frow) * TSEQ + fcol] = *(const f32x4*)&obuf[frow][fcol];
    }
}

// ---------------- fallback: round-0 fp32 kernel (known good, 4.8 ms) ----------------
#define FNT 512
#define FRPB 8
__global__ __launch_bounds__(FNT, 2) void lstm_stack_kernel(
    const float* __restrict__ x,
    const float* __restrict__ W1, const float* __restrict__ U1, const float* __restrict__ b1,
    const float* __restrict__ W2, const float* __restrict__ U2, const float* __restrict__ b2,
    const float* __restrict__ W3, const float* __restrict__ U3, const float* __restrict__ b3,
    const float* __restrict__ W4, const float* __restrict__ U4, const float* __restrict__ b4,
    const float* __restrict__ Wd, const float* __restrict__ bd,
    float* __restrict__ out)
{
    __shared__ float h1s[FRPB][128], c1s[FRPB][128];
    __shared__ float h2s[FRPB][64],  c2s[FRPB][64];
    __shared__ float h3s[FRPB][64],  c3s[FRPB][64];
    __shared__ float h4s[FRPB][128], c4s[FRPB][128];
    __shared__ float zbf[FRPB][512];
    __shared__ float z3xf[FRPB][256];
    __shared__ float xs[FRPB];

    const int tid = threadIdx.x;
    const int r0  = blockIdx.x * FRPB;
    const int jg  = tid & 255;
    const int grp = tid >> 8;
    const int rb  = grp * 4;

    {
        float* p1 = &h1s[0][0]; float* p2 = &c1s[0][0];
        float* p3 = &h4s[0][0]; float* p4 = &c4s[0][0];
        for (int i = tid; i < FRPB * 128; i += FNT) { p1[i]=0.f; p2[i]=0.f; p3[i]=0.f; p4[i]=0.f; }
        float* q1 = &h2s[0][0]; float* q2 = &c2s[0][0];
        float* q3 = &h3s[0][0]; float* q4 = &c3s[0][0];
        for (int i = tid; i < FRPB * 64; i += FNT) { q1[i]=0.f; q2[i]=0.f; q3[i]=0.f; q4[i]=0.f; }
    }
    __syncthreads();

    const float w1j = W1[tid];
    const float b1j = b1[tid];
    const float b2j = b2[jg];

    for (int t = 0; t < TSEQ; ++t) {
        if (tid < FRPB) xs[tid] = x[(r0 + tid) * TSEQ + t];
        __syncthreads();
        {
            float acc[FRPB];
            #pragma unroll
            for (int r = 0; r < FRPB; ++r) acc[r] = 0.f;
            const float* Uc = U1 + tid;
            #pragma unroll 4
            for (int k4 = 0; k4 < 32; ++k4) {
                const float u0 = Uc[(k4*4+0)*512];
                const float u1 = Uc[(k4*4+1)*512];
                const float u2 = Uc[(k4*4+2)*512];
                const float u3 = Uc[(k4*4+3)*512];
                #pragma unroll
                for (int r = 0; r < FRPB; ++r) {
                    const float4 h = ((const float4*)h1s[r])[k4];
                    acc[r] += h.x*u0 + h.y*u1 + h.z*u2 + h.w*u3;
                }
            }
            #pragma unroll
            for (int r = 0; r < FRPB; ++r) zbf[r][tid] = acc[r] + xs[r]*w1j + b1j;
        }
        __syncthreads();
        for (int e = tid; e < FRPB * 128; e += FNT) {
            const int r = e >> 7, hc = e & 127;
            const float zi = zbf[r][hc], zf = zbf[r][128+hc], zg = zbf[r][256+hc], zo = zbf[r][384+hc];
            const float c = sigm(zf)*c1s[r][hc] + sigm(zi)*fmaxf(zg, 0.f);
            c1s[r][hc] = c;
            h1s[r][hc] = sigm(zo)*fmaxf(c, 0.f);
        }
        __syncthreads();
        {
            float acc[4] = {0.f, 0.f, 0.f, 0.f};
            const float* Wc = W2 + jg;
            #pragma unroll 4
            for (int k4 = 0; k4 < 32; ++k4) {
                const float u0 = Wc[(k4*4+0)*256];
                const float u1 = Wc[(k4*4+1)*256];
                const float u2 = Wc[(k4*4+2)*256];
                const float u3 = Wc[(k4*4+3)*256];
                #pragma unroll
                for (int q = 0; q < 4; ++q) {
                    const float4 h = ((const float4*)h1s[rb+q])[k4];
                    acc[q] += h.x*u0 + h.y*u1 + h.z*u2 + h.w*u3;
                }
            }
            const float* Uc = U2 + jg;
            #pragma unroll 4
            for (int k4 = 0; k4 < 16; ++k4) {
                const float u0 = Uc[(k4*4+0)*256];
                const float u1 = Uc[(k4*4+1)*256];
                const float u2 = Uc[(k4*4+2)*256];
                const float u3 = Uc[(k4*4+3)*256];
                #pragma unroll
                for (int q = 0; q < 4; ++q) {
                    const float4 h = ((const float4*)h2s[rb+q])[k4];
                    acc[q] += h.x*u0 + h.y*u1 + h.z*u2 + h.w*u3;
                }
            }
            #pragma unroll
            for (int q = 0; q < 4; ++q) zbf[rb+q][jg] = acc[q] + b2j;
        }
        __syncthreads();
        {
            const int r = tid >> 6, hc = tid & 63;
            const float zi = zbf[r][hc], zf = zbf[r][64+hc], zg = zbf[r][128+hc], zo = zbf[r][192+hc];
            const float c = sigm(zf)*c2s[r][hc] + sigm(zi)*fmaxf(zg, 0.f);
            c2s[r][hc] = c;
            h2s[r][hc] = sigm(zo)*fmaxf(c, 0.f);
        }
        __syncthreads();
    }
    {
        float acc[4] = {0.f, 0.f, 0.f, 0.f};
        const float* Wc = W3 + jg;
        #pragma unroll 4
        for (int k4 = 0; k4 < 16; ++k4) {
            const float u0 = Wc[(k4*4+0)*256];
            const float u1 = Wc[(k4*4+1)*256];
            const float u2 = Wc[(k4*4+2)*256];
            const float u3 = Wc[(k4*4+3)*256];
            #pragma unroll
            for (int q = 0; q < 4; ++q) {
                const float4 h = ((const float4*)h2s[rb+q])[k4];
                acc[q] += h.x*u0 + h.y*u1 + h.z*u2 + h.w*u3;
            }
        }
        const float b3j = b3[jg];
        #pragma unroll
        for (int q = 0; q < 4; ++q) z3xf[rb+q][jg] = acc[q] + b3j;
    }
    __syncthreads();

    const float b4j = b4[tid];
    const float wd0 = Wd[tid & 63];
    const float wd1 = Wd[64 + (tid & 63)];
    const float bd0 = bd[0];

    for (int t = 0; t < TSEQ; ++t) {
        {
            float acc[4];
            #pragma unroll
            for (int q = 0; q < 4; ++q) acc[q] = z3xf[rb+q][jg];
            const float* Uc = U3 + jg;
            #pragma unroll 4
            for (int k4 = 0; k4 < 16; ++k4) {
                const float u0 = Uc[(k4*4+0)*256];
                const float u1 = Uc[(k4*4+1)*256];
                const float u2 = Uc[(k4*4+2)*256];
                const float u3 = Uc[(k4*4+3)*256];
                #pragma unroll
                for (int q = 0; q < 4; ++q) {
                    const float4 h = ((const float4*)h3s[rb+q])[k4];
                    acc[q] += h.x*u0 + h.y*u1 + h.z*u2 + h.w*u3;
                }
            }
            #pragma unroll
            for (int q = 0; q < 4; ++q) zbf[rb+q][jg] = acc[q];
        }
        __syncthreads();
        {
            const int r = tid >> 6, hc = tid & 63;
            const float zi = zbf[r][hc], zf = zbf[r][64+hc], zg = zbf[r][128+hc], zo = zbf[r][192+hc];
            const float c = sigm(zf)*c3s[r][hc] + sigm(zi)*fmaxf(zg, 0.f);
            c3s[r][hc] = c;
            h3s[r][hc] = sigm(zo)*fmaxf(c, 0.f);
        }
        __syncthreads();
        {
            float acc[FRPB];
            #pragma unroll
            for (int r = 0; r < FRPB; ++r) acc[r] = 0.f;
            const float* Wc = W4 + tid;
            #pragma unroll 4
            for (int k4 = 0; k4 < 16; ++k4) {
                const float u0 = Wc[(k4*4+0)*512];
                const float u1 = Wc[(k4*4+1)*512];
                const float u2 = Wc[(k4*4+2)*512];
                const float u3 = Wc[(k4*4+3)*512];
                #pragma unroll
                for (int r = 0; r < FRPB; ++r) {
                    const float4 h = ((const float4*)h3s[r])[k4];
                    acc[r] += h.x*u0 + h.y*u1 + h.z*u2 + h.w*u3;
                }
            }
            const float* Uc = U4 + tid;
            #pragma unroll 4
            for (int k4 = 0; k4 < 32; ++k4) {
                const float u0 = Uc[(k4*4+0)*512];
                const float u1 = Uc[(k4*4+1)*512];
                const float u2 = Uc[(k4*4+2)*512];
                const float u3 = Uc[(k4*4+3)*512];
                #pragma unroll
                for (int r = 0; r < FRPB; ++r) {
                    const float4 h = ((const float4*)h4s[r])[k4];
                    acc[r] += h.x*u0 + h.y*u1 + h.z*u2 + h.w*u3;
                }
            }
            #pragma unroll
            for (int r = 0; r < FRPB; ++r) zbf[r][tid] = acc[r] + b4j;
        }
        __syncthreads();
        for (int e = tid; e < FRPB * 128; e += FNT) {
            const int r = e >> 7, hc = e & 127;
            const float zi = zbf[r][hc], zf = zbf[r][128+hc], zg = zbf[r][256+hc], zo = zbf[r][384+hc];
            const float c = sigm(zf)*c4s[r][hc] + sigm(zi)*fmaxf(zg, 0.f);
            c4s[r][hc] = c;
            h4s[r][hc] = sigm(zo)*fmaxf(c, 0.f);
        }
        __syncthreads();
        {
            const int wv = tid >> 6, ln = tid & 63;
            float v = h4s[wv][ln]*wd0 + h4s[wv][64+ln]*wd1;
            v += __shfl_down(v, 32, 64);
            v += __shfl_down(v, 16, 64);
            v += __shfl_down(v,  8, 64);
            v += __shfl_down(v,  4, 64);
            v += __shfl_down(v,  2, 64);
            v += __shfl_down(v,  1, 64);
            if (ln == 0) out[(r0 + wv) * TSEQ + t] = v + bd0;
        }
    }
}

extern "C" void kernel_launch(void* const* d_in, const int* in_sizes, int n_in,
                              void* d_out, int out_size, void* d_ws, size_t ws_size,
                              hipStream_t stream) {
    const float* x  = (const float*)d_in[0];
    const float* W1 = (const float*)d_in[1];
    const float* U1 = (const float*)d_in[2];
    const float* b1 = (const float*)d_in[3];
    const float* W2 = (const float*)d_in[4];
    const float* U2 = (const float*)d_in[5];
    const float* b2 = (const float*)d_in[6];
    const float* W3 = (const float*)d_in[7];
    const float* U3 = (const float*)d_in[8];
    const float* b3 = (const float*)d_in[9];
    const float* W4 = (const float*)d_in[10];
    const float* U4 = (const float*)d_in[11];
    const float* b4 = (const float*)d_in[12];
    const float* Wd = (const float*)d_in[13];
    const float* bd = (const float*)d_in[14];
    float* out = (float*)d_out;

    if (ws_size >= (size_t)WS_NEEDED) {
        ushort_t* wsp = (ushort_t*)d_ws;
        pack_weights<<<dim3(WS_FRAGS), dim3(64), 0, stream>>>(U1, W2, U2, U3, W4, U4, W3, wsp);
        lstm_mfma_kernel<<<dim3(2048 / 16), dim3(NTH), 0, stream>>>(
            x, W1, b1, b2, b3, b4, Wd, bd, wsp, out);
    } else {
        lstm_stack_kernel<<<dim3(2048 / FRPB), dim3(FNT), 0, stream>>>(
            x, W1, U1, b1, W2, U2, b2, W3, U3, b3, W4, U4, b4, Wd, bd, out);
    }
}

// Round 6
// 757.714 us; speedup vs baseline: 1.7856x; 1.7856x over previous
//
#include <hip/hip_runtime.h>

// LSTM autoencoder B=2048,T=128: L1 LSTM(128,in1) -> L2 LSTM(64,in128) -> Repeat
// -> L3 LSTM(64,in64) -> L4 LSTM(128,in64) -> Dense(1).
// R19 = lag-1 pipeline (R18's PROVEN-CORRECT parity scheme) + R15's per-wave
// work shape + 12 waves.
// R18 post-mortem: 2.7x regression because doubling per-wave L1 coverage
// (32 frags = 128 VGPR) forced full weight streaming on 4 waves with nothing
// co-resident to hide ~32 L2-hit loads/step. The pipeline itself was correct.
// R19: L1 stays 1 col-block/wave (16 frags, R15 shape, 8 waves = waves 4-11);
// L2(t-1) runs CONCURRENTLY on waves 0-3 (lagged -> no intra-step barrier).
// Phase B: L4(t-1) on waves 4-11, L3(t)+dense(t-2) on waves 0-3. ONE barrier
// per step. NTH=768 (12 waves, 3/SIMD; grid=128 means 1 block/CU regardless,
// so the extra waves are free occupancy; VGPR cap ~170 > our ~120).
// Epilogues folded into loop bounds (A: t<=128; B: t<=129); parity formulas
// identical to R18 (absmax-verified) and re-audited at t=0/128/129.

#define TSEQ 128
#define NTH  768
#define BSTR 408   // bU row stride in shorts

typedef __attribute__((ext_vector_type(8))) short bf16x8;
typedef __attribute__((ext_vector_type(4))) float f32x4;
typedef __attribute__((ext_vector_type(2))) float f32x2;
typedef __attribute__((ext_vector_type(4))) short s16x4;
typedef unsigned short ushort_t;

// frag regions in d_ws (units of 512-elem frags, 1KB each); hi even, lo odd (lo unused)
#define FB_L1 0      // U1: K=128 (KT=4), JT=32 -> 256 frags
#define FB_L2 256    // [W2;U2]: K=192 (KT=6), JT=16 -> 192
#define FB_L3 448    // U3: K=64 (KT=2), JT=16 -> 64
#define FB_L4 512    // [W4;U4]: K=192 (KT=6), JT=32 -> 384
#define FB_W3 896    // W3: K=64 (KT=2), JT=16 -> 64
#define WS_FRAGS 960
#define WS_NEEDED (WS_FRAGS * 1024)

__device__ __forceinline__ ushort_t f2bf(float f) {
    union { float f; unsigned u; } a; a.f = f;
    unsigned r = a.u + 0x7FFF + ((a.u >> 16) & 1);
    return (ushort_t)(r >> 16);
}
__device__ __forceinline__ float bf2f(ushort_t h) {
    union { unsigned u; float f; } a; a.u = ((unsigned)h) << 16;
    return a.f;
}
__device__ __forceinline__ float sigm(float z) { return 1.0f / (1.0f + __expf(-z)); }

__device__ __forceinline__ f32x4 MF(bf16x8 a, bf16x8 b, f32x4 c) {
    return __builtin_amdgcn_mfma_f32_16x16x32_bf16(a, b, c, 0, 0, 0);
}

// packed f32x2 -> bf16x2 (RNE), 1 instruction; dst[15:0]=lo, dst[31:16]=hi
__device__ __forceinline__ unsigned cvtpk(float lo, float hi) {
    unsigned r;
    asm("v_cvt_pk_bf16_f32 %0, %1, %2" : "=v"(r) : "v"(lo), "v"(hi));
    return r;
}

// ---------------- weight pack kernel (unchanged layout) ----------------
__global__ void pack_weights(const float* __restrict__ U1, const float* __restrict__ W2,
                             const float* __restrict__ U2, const float* __restrict__ U3,
                             const float* __restrict__ W4, const float* __restrict__ U4,
                             const float* __restrict__ W3, ushort_t* __restrict__ out)
{
    const int f = blockIdx.x;
    const int lane = threadIdx.x;
    int fl, KT, ldm, ksplit = 1 << 30, ld2 = 0;
    const float *base, *base2 = nullptr;
    if (f < 256)      { fl = f;       KT = 4; ldm = 512; base = U1; }
    else if (f < 448) { fl = f - 256; KT = 6; ldm = 256; base = W2; ksplit = 128; base2 = U2; ld2 = 256; }
    else if (f < 512) { fl = f - 448; KT = 2; ldm = 256; base = U3; }
    else if (f < 896) { fl = f - 512; KT = 6; ldm = 512; base = W4; ksplit = 64;  base2 = U4; ld2 = 512; }
    else              { fl = f - 896; KT = 2; ldm = 256; base = W3; }
    const int jt = fl / (KT * 2);
    const int rem = fl % (KT * 2);
    const int kt = rem >> 1;
    const int s = rem & 1;
    const int j = jt * 16 + (lane & 15);
    ushort_t* o = out + f * 512 + lane * 8;
    #pragma unroll
    for (int i = 0; i < 8; ++i) {
        const int k = kt * 32 + (lane >> 4) * 8 + i;
        const float w = (k < ksplit) ? base[k * ldm + j] : base2[(k - ksplit) * ld2 + j];
        const ushort_t hi = f2bf(w);
        o[i] = s ? f2bf(w - bf2f(hi)) : hi;
    }
}

// ---------------- main kernel ----------------
__global__ __launch_bounds__(NTH, 1) void lstm_mfma_kernel(
    const float* __restrict__ x,
    const float* __restrict__ W1, const float* __restrict__ b1,
    const float* __restrict__ b2, const float* __restrict__ b3,
    const float* __restrict__ b4,
    const float* __restrict__ Wd, const float* __restrict__ bd,
    const ushort_t* __restrict__ wsp,
    float* __restrict__ out)
{
    // bU: single bf16 activation plane:
    //  phaseA: h1 ping[0,128)/pong[128,256); h2(s) at 256 + (s&1)*64
    //  phaseB: h3 ping[0,64)/pong[64,128);  h4(s) at 128 + (s&1)*128
    __shared__ __align__(16) ushort_t bU[16][BSTR];      // 13056 B
    __shared__ __align__(16) float obuf[16][128];        //  8192 B
    __shared__ __align__(16) float xls[16][132];         //  8448 B
    __shared__ __align__(16) float w1ls[512], b1ls[512], b4ls[512], b2ls[256];

    const int tid  = threadIdx.x;
    const int wid  = tid >> 6;
    const int lane = tid & 63;
    const int quad = lane >> 4;
    const int l15  = lane & 15;
    const int cb   = wid - 4;              // col-block for waves 4-11
    const int r0   = blockIdx.x * 16;
    const bf16x8* A = (const bf16x8*)wsp;

    // ---- init: zero state, stage x / W1 / biases ----
    {
        unsigned* p = (unsigned*)&bU[0][0];
        for (int i = tid; i < 16 * BSTR / 2; i += NTH) p[i] = 0u;
        if (tid < 512) {
            const int srow = tid >> 5, scol = (tid & 31) * 4;
            *(f32x4*)&xls[srow][scol] = *(const f32x4*)&x[(r0 + srow) * TSEQ + scol];
            w1ls[tid] = W1[tid];
            b1ls[tid] = b1[tid];
            b4ls[tid] = b4[tid];
        }
        if (tid < 256) b2ls[tid] = b2[tid];
    }

    const float wd0 = Wd[lane], wd1 = Wd[64 + lane], bd0 = bd[0];

    __syncthreads();

    // ================= Phase A: waves 4-11 = L1(t), waves 0-3 = L2(t-1) ========
    // One barrier per step. t=TSEQ iteration is the folded L2(127) epilogue.
    {
        float c1r[4] = {0.f, 0.f, 0.f, 0.f};
        float c2r[4] = {0.f, 0.f, 0.f, 0.f};

        for (int t = 0; t <= TSEQ; ++t) {
            const int rb1 = (t & 1) * 128, wb1 = 128 - rb1;   // h1(t-1) / h1(t)

            if (t < TSEQ && wid >= 4) {
                // ---- L1(t): col-block cb, gates fused, c1 in VGPRs (R15 shape) ----
                bf16x8 Bh[4];
                #pragma unroll
                for (int kt = 0; kt < 4; ++kt)
                    Bh[kt] = *(const bf16x8*)&bU[l15][rb1 + kt * 32 + quad * 8];
                const float xr = xls[l15][t];
                f32x4 acc[4];
                #pragma unroll
                for (int g = 0; g < 4; ++g) {
                    const int jt_ = cb + 8 * g;
                    const int jb = jt_ * 16 + quad * 4;
                    f32x4 a = *(const f32x4*)&b1ls[jb];
                    a += xr * *(const f32x4*)&w1ls[jb];
                    #pragma unroll
                    for (int kt = 0; kt < 4; ++kt)
                        a = MF(A[(FB_L1 + (jt_ * 4 + kt) * 2) * 64 + lane], Bh[kt], a);
                    acc[g] = a;
                }
                float hg[4];
                #pragma unroll
                for (int g = 0; g < 4; ++g) {
                    const float zi = acc[0][g];
                    const float zf = acc[1][g];
                    const float zg = acc[2][g];
                    const float zo = acc[3][g];
                    const float c = sigm(zf) * c1r[g] + sigm(zi) * fmaxf(zg, 0.f);
                    c1r[g] = c;
                    hg[g] = sigm(zo) * fmaxf(c, 0.f);
                }
                uint2 hv;
                hv.x = cvtpk(hg[0], hg[1]);
                hv.y = cvtpk(hg[2], hg[3]);
                *(uint2*)&bU[l15][wb1 + cb * 16 + quad * 4] = hv;
            } else if (t > 0 && wid < 4) {
                // ---- L2(t-1): reads h1(t-1)@rb1, h2(t-2); writes h2(t-1) ----
                const int h2rd = 256 + (t & 1) * 64;          // h2(t-2)
                const int h2wr = 256 + ((t & 1) ^ 1) * 64;    // h2(t-1)
                bf16x8 Bh[6];
                #pragma unroll
                for (int kt = 0; kt < 4; ++kt)
                    Bh[kt] = *(const bf16x8*)&bU[l15][rb1 + kt * 32 + quad * 8];
                Bh[4] = *(const bf16x8*)&bU[l15][h2rd + quad * 8];
                Bh[5] = *(const bf16x8*)&bU[l15][h2rd + 32 + quad * 8];
                f32x4 acc[4];
                #pragma unroll
                for (int g = 0; g < 4; ++g) {
                    f32x4 a = *(const f32x4*)&b2ls[(4 * g + wid) * 16 + quad * 4];
                    #pragma unroll
                    for (int kt = 0; kt < 6; ++kt)
                        a = MF(A[(FB_L2 + ((4 * g + wid) * 6 + kt) * 2) * 64 + lane], Bh[kt], a);
                    acc[g] = a;
                }
                float hg[4];
                #pragma unroll
                for (int e = 0; e < 4; ++e) {
                    const float zi = acc[0][e];
                    const float zf = acc[1][e];
                    const float zg = acc[2][e];
                    const float zo = acc[3][e];
                    const float c = sigm(zf) * c2r[e] + sigm(zi) * fmaxf(zg, 0.f);
                    c2r[e] = c;
                    hg[e] = sigm(zo) * fmaxf(c, 0.f);
                }
                uint2 hv;
                hv.x = cvtpk(hg[0], hg[1]);
                hv.y = cvtpk(hg[2], hg[3]);
                *(uint2*)&bU[l15][h2wr + wid * 16 + quad * 4] = hv;
            }
            __syncthreads();
        }
    }

    // ================= z3r = b3 + h2_final @ W3 (registers, waves 0-3) =========
    // h2(127) written by the folded epilogue at h2wr(128) = 320.
    f32x4 z3r[4];
    if (wid < 4) {
        const bf16x8 Bh0 = *(const bf16x8*)&bU[l15][320 + quad * 8];
        const bf16x8 Bh1 = *(const bf16x8*)&bU[l15][320 + 32 + quad * 8];
        #pragma unroll
        for (int g = 0; g < 4; ++g) {
            const int jt = 4 * g + wid;
            f32x4 a = *(const f32x4*)&b3[jt * 16 + quad * 4];
            a = MF(A[(FB_W3 + (jt * 2 + 0) * 2) * 64 + lane], Bh0, a);
            a = MF(A[(FB_W3 + (jt * 2 + 1) * 2) * 64 + lane], Bh1, a);
            z3r[g] = a;
        }
    }
    __syncthreads();
    // re-zero activation plane for phase B
    {
        unsigned* p = (unsigned*)&bU[0][0];
        for (int i = tid; i < 16 * BSTR / 2; i += NTH) p[i] = 0u;
    }
    __syncthreads();

    // ================= Phase B: waves 0-3 = L3(t)+dense(t-2), waves 4-11 = L4(t-1)
    // One barrier per step. t=TSEQ: L4(127)+dense(126); t=TSEQ+1: dense(127).
    {
        float c3r[4] = {0.f, 0.f, 0.f, 0.f};
        float c4r[4] = {0.f, 0.f, 0.f, 0.f};

        for (int t = 0; t <= TSEQ + 1; ++t) {
            const int rb3 = (t & 1) * 64, wb3 = 64 - rb3;     // h3(t-1) / h3(t)
            const int b4rd = 128 + (t & 1) * 128;             // h4(t-2)
            const int b4wr = 128 + ((t & 1) ^ 1) * 128;       // h4(t-1)

            if (wid < 4) {
                if (t < TSEQ) {
                    // ---- L3(t): acc init = z3r (carries b3 + W3·h2) ----
                    const bf16x8 Bh0 = *(const bf16x8*)&bU[l15][rb3 + quad * 8];
                    const bf16x8 Bh1 = *(const bf16x8*)&bU[l15][rb3 + 32 + quad * 8];
                    f32x4 acc[4];
                    #pragma unroll
                    for (int g = 0; g < 4; ++g) {
                        f32x4 a = z3r[g];
                        a = MF(A[(FB_L3 + ((4 * g + wid) * 2 + 0) * 2) * 64 + lane], Bh0, a);
                        a = MF(A[(FB_L3 + ((4 * g + wid) * 2 + 1) * 2) * 64 + lane], Bh1, a);
                        acc[g] = a;
                    }
                    float hg[4];
                    #pragma unroll
                    for (int e = 0; e < 4; ++e) {
                        const float zi = acc[0][e];
                        const float zf = acc[1][e];
                        const float zg = acc[2][e];
                        const float zo = acc[3][e];
                        const float c = sigm(zf) * c3r[e] + sigm(zi) * fmaxf(zg, 0.f);
                        c3r[e] = c;
                        hg[e] = sigm(zo) * fmaxf(c, 0.f);
                    }
                    uint2 hv;
                    hv.x = cvtpk(hg[0], hg[1]);
                    hv.y = cvtpk(hg[2], hg[3]);
                    *(uint2*)&bU[l15][wb3 + wid * 16 + quad * 4] = hv;
                }
                // ---- dense(t-2): reads h4(t-2)@b4rd (written last iter, safe) ----
                if (t > 1) {
                    #pragma unroll
                    for (int e = 0; e < 4; ++e) {
                        const int r = wid + 4 * e;
                        const float h0 = bf2f(bU[r][b4rd + lane]);
                        const float h1_ = bf2f(bU[r][b4rd + 64 + lane]);
                        float v = h0 * wd0 + h1_ * wd1;
                        v += __shfl_down(v, 32);
                        v += __shfl_down(v, 16);
                        v += __shfl_down(v, 8);
                        v += __shfl_down(v, 4);
                        v += __shfl_down(v, 2);
                        v += __shfl_down(v, 1);
                        if (lane == 0) obuf[r][t - 2] = v + bd0;
                    }
                }
            } else if (t > 0 && t <= TSEQ) {
                // ---- L4(t-1): col-block cb; K=192 = [h3(t-1)@rb3 ; h4(t-2)@b4rd] ----
                bf16x8 Bh[6];
                #pragma unroll
                for (int kt = 0; kt < 2; ++kt)
                    Bh[kt] = *(const bf16x8*)&bU[l15][rb3 + kt * 32 + quad * 8];
                #pragma unroll
                for (int kt = 2; kt < 6; ++kt)
                    Bh[kt] = *(const bf16x8*)&bU[l15][b4rd + (kt - 2) * 32 + quad * 8];
                f32x4 acc[4];
                #pragma unroll
                for (int g = 0; g < 4; ++g) {
                    const int jt_ = cb + 8 * g;
                    f32x4 a = *(const f32x4*)&b4ls[jt_ * 16 + quad * 4];
                    #pragma unroll
                    for (int kt = 0; kt < 6; ++kt)
                        a = MF(A[(FB_L4 + (jt_ * 6 + kt) * 2) * 64 + lane], Bh[kt], a);
                    acc[g] = a;
                }
                float hg[4];
                #pragma unroll
                for (int g = 0; g < 4; ++g) {
                    const float zi = acc[0][g];
                    const float zf = acc[1][g];
                    const float zg = acc[2][g];
                    const float zo = acc[3][g];
                    const float c = sigm(zf) * c4r[g] + sigm(zi) * fmaxf(zg, 0.f);
                    c4r[g] = c;
                    hg[g] = sigm(zo) * fmaxf(c, 0.f);
                }
                uint2 hv;
                hv.x = cvtpk(hg[0], hg[1]);
                hv.y = cvtpk(hg[2], hg[3]);
                *(uint2*)&bU[l15][b4wr + cb * 16 + quad * 4] = hv;
            }
            __syncthreads();
        }
    }

    // coalesced flush: 4 floats/thread on first 512 threads
    if (tid < 512) {
        const int frow = tid >> 5;
        const int fcol = (tid & 31) * 4;
        *(f32x4*)&out[(r0 + frow) * TSEQ + fcol] = *(const f32x4*)&obuf[frow][fcol];
    }
}

// ---------------- fallback: round-0 fp32 kernel (known good, 4.8 ms) ----------------
#define FNT 512
#define FRPB 8
__global__ __launch_bounds__(FNT, 2) void lstm_stack_kernel(
    const float* __restrict__ x,
    const float* __restrict__ W1, const float* __restrict__ U1, const float* __restrict__ b1,
    const float* __restrict__ W2, const float* __restrict__ U2, const float* __restrict__ b2,
    const float* __restrict__ W3, const float* __restrict__ U3, const float* __restrict__ b3,
    const float* __restrict__ W4, const float* __restrict__ U4, const float* __restrict__ b4,
    const float* __restrict__ Wd, const float* __restrict__ bd,
    float* __restrict__ out)
{
    __shared__ float h1s[FRPB][128], c1s[FRPB][128];
    __shared__ float h2s[FRPB][64],  c2s[FRPB][64];
    __shared__ float h3s[FRPB][64],  c3s[FRPB][64];
    __shared__ float h4s[FRPB][128], c4s[FRPB][128];
    __shared__ float zbf[FRPB][512];
    __shared__ float z3xf[FRPB][256];
    __shared__ float xs[FRPB];

    const int tid = threadIdx.x;
    const int r0  = blockIdx.x * FRPB;
    const int jg  = tid & 255;
    const int grp = tid >> 8;
    const int rb  = grp * 4;

    {
        float* p1 = &h1s[0][0]; float* p2 = &c1s[0][0];
        float* p3 = &h4s[0][0]; float* p4 = &c4s[0][0];
        for (int i = tid; i < FRPB * 128; i += FNT) { p1[i]=0.f; p2[i]=0.f; p3[i]=0.f; p4[i]=0.f; }
        float* q1 = &h2s[0][0]; float* q2 = &c2s[0][0];
        float* q3 = &h3s[0][0]; float* q4 = &c3s[0][0];
        for (int i = tid; i < FRPB * 64; i += FNT) { q1[i]=0.f; q2[i]=0.f; q3[i]=0.f; q4[i]=0.f; }
    }
    __syncthreads();

    const float w1j = W1[tid];
    const float b1j = b1[tid];
    const float b2j = b2[jg];

    for (int t = 0; t < TSEQ; ++t) {
        if (tid < FRPB) xs[tid] = x[(r0 + tid) * TSEQ + t];
        __syncthreads();
        {
            float acc[FRPB];
            #pragma unroll
            for (int r = 0; r < FRPB; ++r) acc[r] = 0.f;
            const float* Uc = U1 + tid;
            #pragma unroll 4
            for (int k4 = 0; k4 < 32; ++k4) {
                const float u0 = Uc[(k4*4+0)*512];
                const float u1 = Uc[(k4*4+1)*512];
                const float u2 = Uc[(k4*4+2)*512];
                const float u3 = Uc[(k4*4+3)*512];
                #pragma unroll
                for (int r = 0; r < FRPB; ++r) {
                    const float4 h = ((const float4*)h1s[r])[k4];
                    acc[r] += h.x*u0 + h.y*u1 + h.z*u2 + h.w*u3;
                }
            }
            #pragma unroll
            for (int r = 0; r < FRPB; ++r) zbf[r][tid] = acc[r] + xs[r]*w1j + b1j;
        }
        __syncthreads();
        for (int e = tid; e < FRPB * 128; e += FNT) {
            const int r = e >> 7, hc = e & 127;
            const float zi = zbf[r][hc], zf = zbf[r][128+hc], zg = zbf[r][256+hc], zo = zbf[r][384+hc];
            const float c = sigm(zf)*c1s[r][hc] + sigm(zi)*fmaxf(zg, 0.f);
            c1s[r][hc] = c;
            h1s[r][hc] = sigm(zo)*fmaxf(c, 0.f);
        }
        __syncthreads();
        {
            float acc[4] = {0.f, 0.f, 0.f, 0.f};
            const float* Wc = W2 + jg;
            #pragma unroll 4
            for (int k4 = 0; k4 < 32; ++k4) {
                const float u0 = Wc[(k4*4+0)*256];
                const float u1 = Wc[(k4*4+1)*256];
                const float u2 = Wc[(k4*4+2)*256];
                const float u3 = Wc[(k4*4+3)*256];
                #pragma unroll
                for (int q = 0; q < 4; ++q) {
                    const float4 h = ((const float4*)h1s[rb+q])[k4];
                    acc[q] += h.x*u0 + h.y*u1 + h.z*u2 + h.w*u3;
                }
            }
            const float* Uc = U2 + jg;
            #pragma unroll 4
            for (int k4 = 0; k4 < 16; ++k4) {
                const float u0 = Uc[(k4*4+0)*256];
                const float u1 = Uc[(k4*4+1)*256];
                const float u2 = Uc[(k4*4+2)*256];
                const float u3 = Uc[(k4*4+3)*256];
                #pragma unroll
                for (int q = 0; q < 4; ++q) {
                    const float4 h = ((const float4*)h2s[rb+q])[k4];
                    acc[q] += h.x*u0 + h.y*u1 + h.z*u2 + h.w*u3;
                }
            }
            #pragma unroll
            for (int q = 0; q < 4; ++q) zbf[rb+q][jg] = acc[q] + b2j;
        }
        __syncthreads();
        {
            const int r = tid >> 6, hc = tid & 63;
            const float zi = zbf[r][hc], zf = zbf[r][64+hc], zg = zbf[r][128+hc], zo = zbf[r][192+hc];
            const float c = sigm(zf)*c2s[r][hc] + sigm(zi)*fmaxf(zg, 0.f);
            c2s[r][hc] = c;
            h2s[r][hc] = sigm(zo)*fmaxf(c, 0.f);
        }
        __syncthreads();
    }
    {
        float acc[4] = {0.f, 0.f, 0.f, 0.f};
        const float* Wc = W3 + jg;
        #pragma unroll 4
        for (int k4 = 0; k4 < 16; ++k4) {
            const float u0 = Wc[(k4*4+0)*256];
            const float u1 = Wc[(k4*4+1)*256];
            const float u2 = Wc[(k4*4+2)*256];
            const float u3 = Wc[(k4*4+3)*256];
            #pragma unroll
            for (int q = 0; q < 4; ++q) {
                const float4 h = ((const float4*)h2s[rb+q])[k4];
                acc[q] += h.x*u0 + h.y*u1 + h.z*u2 + h.w*u3;
            }
        }
        const float b3j = b3[jg];
        #pragma unroll
        for (int q = 0; q < 4; ++q) z3xf[rb+q][jg] = acc[q] + b3j;
    }
    __syncthreads();

    const float b4j = b4[tid];
    const float wd0 = Wd[tid & 63];
    const float wd1 = Wd[64 + (tid & 63)];
    const float bd0 = bd[0];

    for (int t = 0; t < TSEQ; ++t) {
        {
            float acc[4];
            #pragma unroll
            for (int q = 0; q < 4; ++q) acc[q] = z3xf[rb+q][jg];
            const float* Uc = U3 + jg;
            #pragma unroll 4
            for (int k4 = 0; k4 < 16; ++k4) {
                const float u0 = Uc[(k4*4+0)*256];
                const float u1 = Uc[(k4*4+1)*256];
                const float u2 = Uc[(k4*4+2)*256];
                const float u3 = Uc[(k4*4+3)*256];
                #pragma unroll
                for (int q = 0; q < 4; ++q) {
                    const float4 h = ((const float4*)h3s[rb+q])[k4];
                    acc[q] += h.x*u0 + h.y*u1 + h.z*u2 + h.w*u3;
                }
            }
            #pragma unroll
            for (int q = 0; q < 4; ++q) zbf[rb+q][jg] = acc[q];
        }
        __syncthreads();
        {
            const int r = tid >> 6, hc = tid & 63;
            const float zi = zbf[r][hc], zf = zbf[r][64+hc], zg = zbf[r][128+hc], zo = zbf[r][192+hc];
            const float c = sigm(zf)*c3s[r][hc] + sigm(zi)*fmaxf(zg, 0.f);
            c3s[r][hc] = c;
            h3s[r][hc] = sigm(zo)*fmaxf(c, 0.f);
        }
        __syncthreads();
        {
            float acc[FRPB];
            #pragma unroll
            for (int r = 0; r < FRPB; ++r) acc[r] = 0.f;
            const float* Wc = W4 + tid;
            #pragma unroll 4
            for (int k4 = 0; k4 < 16; ++k4) {
                const float u0 = Wc[(k4*4+0)*512];
                const float u1 = Wc[(k4*4+1)*512];
                const float u2 = Wc[(k4*4+2)*512];
                const float u3 = Wc[(k4*4+3)*512];
                #pragma unroll
                for (int r = 0; r < FRPB; ++r) {
                    const float4 h = ((const float4*)h3s[r])[k4];
                    acc[r] += h.x*u0 + h.y*u1 + h.z*u2 + h.w*u3;
                }
            }
            const float* Uc = U4 + tid;
            #pragma unroll 4
            for (int k4 = 0; k4 < 32; ++k4) {
                const float u0 = Uc[(k4*4+0)*512];
                const float u1 = Uc[(k4*4+1)*512];
                const float u2 = Uc[(k4*4+2)*512];
                const float u3 = Uc[(k4*4+3)*512];
                #pragma unroll
                for (int r = 0; r < FRPB; ++r) {
                    const float4 h = ((const float4*)h4s[r])[k4];
                    acc[r] += h.x*u0 + h.y*u1 + h.z*u2 + h.w*u3;
                }
            }
            #pragma unroll
            for (int r = 0; r < FRPB; ++r) zbf[r][tid] = acc[r] + b4j;
        }
        __syncthreads();
        for (int e = tid; e < FRPB * 128; e += FNT) {
            const int r = e >> 7, hc = e & 127;
            const float zi = zbf[r][hc], zf = zbf[r][128+hc], zg = zbf[r][256+hc], zo = zbf[r][384+hc];
            const float c = sigm(zf)*c4s[r][hc] + sigm(zi)*fmaxf(zg, 0.f);
            c4s[r][hc] = c;
            h4s[r][hc] = sigm(zo)*fmaxf(c, 0.f);
        }
        __syncthreads();
        {
            const int wv = tid >> 6, ln = tid & 63;
            float v = h4s[wv][ln]*wd0 + h4s[wv][64+ln]*wd1;
            v += __shfl_down(v, 32, 64);
            v += __shfl_down(v, 16, 64);
            v += __shfl_down(v,  8, 64);
            v += __shfl_down(v,  4, 64);
            v += __shfl_down(v,  2, 64);
            v += __shfl_down(v,  1, 64);
            if (ln == 0) out[(r0 + wv) * TSEQ + t] = v + bd0;
        }
    }
}

extern "C" void kernel_launch(void* const* d_in, const int* in_sizes, int n_in,
                              void* d_out, int out_size, void* d_ws, size_t ws_size,
                              hipStream_t stream) {
    const float* x  = (const float*)d_in[0];
    const float* W1 = (const float*)d_in[1];
    const float* U1 = (const float*)d_in[2];
    const float* b1 = (const float*)d_in[3];
    const float* W2 = (const float*)d_in[4];
    const float* U2 = (const float*)d_in[5];
    const float* b2 = (const float*)d_in[6];
    const float* W3 = (const float*)d_in[7];
    const float* U3 = (const float*)d_in[8];
    const float* b3 = (const float*)d_in[9];
    const float* W4 = (const float*)d_in[10];
    const float* U4 = (const float*)d_in[11];
    const float* b4 = (const float*)d_in[12];
    const float* Wd = (const float*)d_in[13];
    const float* bd = (const float*)d_in[14];
    float* out = (float*)d_out;

    if (ws_size >= (size_t)WS_NEEDED) {
        ushort_t* wsp = (ushort_t*)d_ws;
        pack_weights<<<dim3(WS_FRAGS), dim3(64), 0, stream>>>(U1, W2, U2, U3, W4, U4, W3, wsp);
        lstm_mfma_kernel<<<dim3(2048 / 16), dim3(NTH), 0, stream>>>(
            x, W1, b1, b2, b3, b4, Wd, bd, wsp, out);
    } else {
        lstm_stack_kernel<<<dim3(2048 / FRPB), dim3(FNT), 0, stream>>>(
            x, W1, U1, b1, W2, U2, b2, W3, U3, b3, W4, U4, b4, Wd, bd, out);
    }
}